// Round 2
// baseline (8253.619 us; speedup 1.0000x reference)
//
#include <hip/hip_runtime.h>
#include <cstddef>
#include <cstdint>

// Problem constants
#define TT 256
#define BB 64
#define NTAG 34
// M = TT*BB = 16384

__device__ __forceinline__ float sigf(float x) { return 1.0f / (1.0f + expf(-x)); }

// ---------------------------------------------------------------------------
// fp32 tiled GEMM: out[m][n] = sum_k A[m][k] * W[n][k] + biasA[n] (+ biasB[n])
// A row source: direct (m*K) or gathered (gidx[m]*K) for the embedding lookup.
// xp_mode=1: store to xp[dir][m][1024] layout (dir = n>>10). else ld=Nvalid.
// BM=BN=64, BK=32, 256 threads, 4x4 micro-tile.
// ---------------------------------------------------------------------------
__global__ __launch_bounds__(256) void gemm_k(
    const float* __restrict__ Abase, const int* __restrict__ gidx,
    const float* __restrict__ W, const float* __restrict__ biasA,
    const float* __restrict__ biasB, float* __restrict__ out,
    int M, int K, int Nvalid, int xp_mode) {
  __shared__ float As[32][68];  // [k][m], +4 pad keeps float4 alignment
  __shared__ float Bs[32][68];  // [k][n]
  int tid = threadIdx.x;
  int m0 = blockIdx.x * 64;
  int n0 = blockIdx.y * 64;
  int tx = tid & 15, ty = tid >> 4;
  int lk = (tid & 7) * 4;  // k offset 0..28
  int lr = tid >> 3;       // row 0..31 (and +32)

  float acc[4][4] = {};

  const float* arow0;
  const float* arow1;
  {
    int ma = m0 + lr, mb = m0 + lr + 32;
    size_t ra = gidx ? (size_t)gidx[ma] : (size_t)ma;
    size_t rb = gidx ? (size_t)gidx[mb] : (size_t)mb;
    arow0 = Abase + ra * (size_t)K;
    arow1 = Abase + rb * (size_t)K;
  }
  int nA = n0 + lr, nB = n0 + lr + 32;
  const float* wr0 = W + (size_t)nA * K;
  const float* wr1 = W + (size_t)nB * K;
  bool v0 = nA < Nvalid, v1 = nB < Nvalid;

  for (int k0 = 0; k0 < K; k0 += 32) {
    float4 a0 = *(const float4*)(arow0 + k0 + lk);
    float4 a1 = *(const float4*)(arow1 + k0 + lk);
    float4 b0 = v0 ? *(const float4*)(wr0 + k0 + lk) : make_float4(0, 0, 0, 0);
    float4 b1 = v1 ? *(const float4*)(wr1 + k0 + lk) : make_float4(0, 0, 0, 0);
    __syncthreads();  // previous iteration's compute done before overwrite
    As[lk + 0][lr] = a0.x; As[lk + 1][lr] = a0.y; As[lk + 2][lr] = a0.z; As[lk + 3][lr] = a0.w;
    As[lk + 0][lr + 32] = a1.x; As[lk + 1][lr + 32] = a1.y; As[lk + 2][lr + 32] = a1.z; As[lk + 3][lr + 32] = a1.w;
    Bs[lk + 0][lr] = b0.x; Bs[lk + 1][lr] = b0.y; Bs[lk + 2][lr] = b0.z; Bs[lk + 3][lr] = b0.w;
    Bs[lk + 0][lr + 32] = b1.x; Bs[lk + 1][lr + 32] = b1.y; Bs[lk + 2][lr + 32] = b1.z; Bs[lk + 3][lr + 32] = b1.w;
    __syncthreads();
#pragma unroll
    for (int k = 0; k < 32; ++k) {
      float4 av = *(const float4*)&As[k][ty * 4];
      float4 bv = *(const float4*)&Bs[k][tx * 4];
#pragma unroll
      for (int i = 0; i < 4; ++i) {
        float a = (&av.x)[i];
        acc[i][0] += a * bv.x;
        acc[i][1] += a * bv.y;
        acc[i][2] += a * bv.z;
        acc[i][3] += a * bv.w;
      }
    }
  }
#pragma unroll
  for (int i = 0; i < 4; ++i) {
    int m = m0 + ty * 4 + i;
#pragma unroll
    for (int j = 0; j < 4; ++j) {
      int n = n0 + tx * 4 + j;
      if (n < Nvalid) {
        float v = acc[i][j] + biasA[n] + (biasB ? biasB[n] : 0.0f);
        if (xp_mode)
          out[((size_t)(n >> 10) * M + m) * 1024 + (n & 1023)] = v;
        else
          out[(size_t)m * Nvalid + n] = v;
      }
    }
  }
}

// ---------------------------------------------------------------------------
// Register-stationary LSTM recurrence.
// 256 blocks = 2 dirs x 16 batch-groups(4 batches) x 8 unit-slices(32 units).
// Mapping: js = blk>>5 (unit slice), rem = blk&31 -> d = rem>>4, bg = rem&15;
// groups of 8 cooperating blocks {rem, rem+32, ...} share XCD under
// round-robin dispatch. Thread (jl = tid>>3, kseg = tid&7) holds
// w[4 gates][32 k] (k = kseg+8i) in 128 VGPRs, loaded once. Per step:
// read h (1 KB) from device-coherent exchange buffer, GEMV, butterfly-reduce
// over kseg lanes, gate nonlinearities for (unit j, batch kseg&3), write h
// back, 8-block atomic barrier. Weights NEVER re-read -> removes the per-CU
// L1 bandwidth wall that made round-1 lstm_rec 9.7 us/step.
// ---------------------------------------------------------------------------
__global__ __launch_bounds__(256, 2) void lstm_fused(
    const float* __restrict__ xp,    // [2][M][1024]
    const float* __restrict__ whh,   // [2][1024][256]
    const int* __restrict__ lengths,
    float* __restrict__ out,         // [M][512]
    float* hx,                       // [2 buf][2 d][16 bg][256 k][4 b]
    int* cnt,                        // [32 groups][16 pad]
    int T, int B) {
  __shared__ float4 hS[256];
  int blk = blockIdx.x;
  int js = blk >> 5;
  int rem = blk & 31;
  int d = rem >> 4;
  int bg = rem & 15;
  int tid = threadIdx.x;
  int jl = tid >> 3;    // 0..31 local unit
  int kseg = tid & 7;   // 0..7 k segment
  int j = js * 32 + jl; // global unit 0..255
  int bl = kseg & 3;    // batch lane (kseg<4 active for state/store)
  int batch = bg * 4 + bl;
  int len = lengths[batch];
  size_t M = (size_t)T * B;

  // Load stationary weights: w[g][i] = whh[d][g*256+j][kseg+8i].
  // All 8 ksegs of a unit collectively touch the full 1KB row -> cache lines
  // fully used; one-time cost.
  float w[4][32];
#pragma unroll
  for (int g = 0; g < 4; ++g) {
    const float* wr = whh + ((size_t)d * 1024 + g * 256 + j) * 256 + kseg;
#pragma unroll
    for (int i = 0; i < 32; ++i) w[g][i] = wr[8 * i];
  }

  float c = 0.0f;
  int* mycnt = cnt + rem * 16;

  for (int s = 0; s < T; ++s) {
    int t = d ? (T - 1 - s) : s;
    // xp gate biases for (j, batch) — independent of h, issue early
    const float* xr = xp + ((size_t)d * M + (size_t)t * B + batch) * 1024 + j;
    float xg0 = xr[0], xg1 = xr[256], xg2 = xr[512], xg3 = xr[768];

    // Load h exchange buf[s&1] -> LDS (agent-scope loads: bypass stale L1/L2)
    {
      const float* hb = hx + ((((size_t)(s & 1) * 2 + d) * 16 + bg) * 1024) + tid * 4;
      float4 hv;
      hv.x = __hip_atomic_load(hb + 0, __ATOMIC_RELAXED, __HIP_MEMORY_SCOPE_AGENT);
      hv.y = __hip_atomic_load(hb + 1, __ATOMIC_RELAXED, __HIP_MEMORY_SCOPE_AGENT);
      hv.z = __hip_atomic_load(hb + 2, __ATOMIC_RELAXED, __HIP_MEMORY_SCOPE_AGENT);
      hv.w = __hip_atomic_load(hb + 3, __ATOMIC_RELAXED, __HIP_MEMORY_SCOPE_AGENT);
      hS[tid] = hv;
    }
    __syncthreads();

    // GEMV: acc[g][b] = sum over my 32 k of w[g][k]*h[k][b]
    float acc[4][4];
#pragma unroll
    for (int g = 0; g < 4; ++g)
#pragma unroll
      for (int b = 0; b < 4; ++b) acc[g][b] = 0.0f;
#pragma unroll
    for (int i = 0; i < 32; ++i) {
      float4 hv = hS[kseg + 8 * i];  // banks (4*kseg..) -> conflict-free
#pragma unroll
      for (int g = 0; g < 4; ++g) {
        acc[g][0] += w[g][i] * hv.x;
        acc[g][1] += w[g][i] * hv.y;
        acc[g][2] += w[g][i] * hv.z;
        acc[g][3] += w[g][i] * hv.w;
      }
    }

    // Butterfly reduce across the 8 kseg lanes (tid low 3 bits)
    float gate[4];
#pragma unroll
    for (int g = 0; g < 4; ++g) {
#pragma unroll
      for (int b = 0; b < 4; ++b) {
        float v = acc[g][b];
        v += __shfl_xor(v, 1);
        v += __shfl_xor(v, 2);
        v += __shfl_xor(v, 4);
        acc[g][b] = v;
      }
      gate[g] = bl == 0 ? acc[g][0] : bl == 1 ? acc[g][1]
              : bl == 2 ? acc[g][2] : acc[g][3];
    }

    bool m = t < len;
    float hprev = ((const float*)hS)[j * 4 + bl];
    float ig = sigf(gate[0] + xg0);
    float fg = sigf(gate[1] + xg1);
    float gg = tanhf(gate[2] + xg2);
    float og = sigf(gate[3] + xg3);
    float cn = fg * c + ig * gg;
    float hn = og * tanhf(cn);
    if (m) c = cn;
    float hkeep = m ? hn : hprev;

    if (kseg < 4) {
      out[((size_t)t * B + batch) * 512 + d * 256 + j] = m ? hkeep : 0.0f;
      if (s + 1 < T) {
        float* hw = hx + ((((size_t)((s + 1) & 1) * 2 + d) * 16 + bg) * 1024) + j * 4 + bl;
        __hip_atomic_store(hw, hkeep, __ATOMIC_RELAXED, __HIP_MEMORY_SCOPE_AGENT);
      }
    }

    if (s + 1 < T) {
      __syncthreads();  // all waves' hx stores drained (s_barrier waits vmcnt)
      if (tid == 0) {
        __hip_atomic_fetch_add(mycnt, 1, __ATOMIC_RELEASE, __HIP_MEMORY_SCOPE_AGENT);
        int target = 8 * (s + 1);
        int guard = 0;
        while (__hip_atomic_load(mycnt, __ATOMIC_ACQUIRE, __HIP_MEMORY_SCOPE_AGENT) < target) {
          __builtin_amdgcn_s_sleep(1);
          if (++guard > (1 << 22)) break;  // hang-preventer; deadlock -> wrong result, not a hung bench
        }
      }
      __syncthreads();
    }
  }
}

// ---------------------------------------------------------------------------
// Viterbi: one block (one wave) per batch element. Forward max-sum with
// first-occurrence argmax (strict >, i ascending = jnp.argmax semantics),
// masked steps keep score and store identity backpointers. Lane 0 backtracks.
// ---------------------------------------------------------------------------
__global__ __launch_bounds__(64) void viterbi_k(
    const float* __restrict__ em, const int* __restrict__ lengths,
    const float* __restrict__ startT, const float* __restrict__ endT,
    const float* __restrict__ trans, int* __restrict__ hist,
    int* __restrict__ outTags, int T, int B) {
  __shared__ float tr[NTAG * NTAG];
  __shared__ float sc[NTAG];
  __shared__ float ns[NTAG];
  int b = blockIdx.x;
  int j = threadIdx.x;
  for (int i = j; i < NTAG * NTAG; i += 64) tr[i] = trans[i];
  int len = lengths[b];
  if (j < NTAG) sc[j] = startT[j] + em[(size_t)b * NTAG + j];
  __syncthreads();
  for (int t = 1; t < T; ++t) {
    if (j < NTAG) {
      float best = -3.0e38f;
      int arg = 0;
      for (int i = 0; i < NTAG; ++i) {
        float v = sc[i] + tr[i * NTAG + j];
        if (v > best) { best = v; arg = i; }
      }
      bool m = t < len;
      float e = em[((size_t)t * B + b) * NTAG + j];
      ns[j] = m ? (best + e) : sc[j];
      hist[((size_t)(t - 1) * B + b) * NTAG + j] = m ? arg : j;
    }
    __syncthreads();
    if (j < NTAG) sc[j] = ns[j];
    __syncthreads();
  }
  if (j == 0) {
    float best = -3.0e38f;
    int arg = 0;
    for (int i = 0; i < NTAG; ++i) {
      float v = sc[i] + endT[i];
      if (v > best) { best = v; arg = i; }
    }
    int tag = arg;
    outTags[(size_t)(T - 1) * B + b] = (T - 1 < len) ? tag : 0;
    for (int t = T - 2; t >= 0; --t) {
      tag = hist[((size_t)t * B + b) * NTAG + tag];
      outTags[(size_t)t * B + b] = (t < len) ? tag : 0;
    }
  }
}

extern "C" void kernel_launch(void* const* d_in, const int* in_sizes, int n_in,
                              void* d_out, int out_size, void* d_ws, size_t ws_size,
                              hipStream_t stream) {
  const int* x = (const int*)d_in[0];            // (T,B) int32
  const int* lens = (const int*)d_in[1];         // (B,)
  const float* embed = (const float*)d_in[2];    // (VOCAB,256)
  const float* w_ih0 = (const float*)d_in[3];    // (2,1024,256)
  const float* w_hh0 = (const float*)d_in[4];    // (2,1024,256)
  const float* b_ih0 = (const float*)d_in[5];    // (2,1024)
  const float* b_hh0 = (const float*)d_in[6];
  const float* w_ih1 = (const float*)d_in[7];    // (2,1024,512)
  const float* w_hh1 = (const float*)d_in[8];    // (2,1024,256)
  const float* b_ih1 = (const float*)d_in[9];
  const float* b_hh1 = (const float*)d_in[10];
  const float* w_lin = (const float*)d_in[11];   // (34,512)
  const float* b_lin = (const float*)d_in[12];   // (34,)
  const float* startT = (const float*)d_in[13];
  const float* endT = (const float*)d_in[14];
  const float* trans = (const float*)d_in[15];   // (34,34)
  int* outTags = (int*)d_out;                    // (T,B) int32

  const int T = TT, B = BB;
  const int M = T * B;  // 16384

  // Workspace layout (~197 MiB total)
  char* ws = (char*)d_ws;
  const size_t SZ_XP = 2ull * M * 1024 * 4;    // 134217728
  const size_t SZ_H = (size_t)M * 512 * 4;     // 33554432
  const size_t SZ_EM = (size_t)M * NTAG * 4;   // 2228224
  const size_t SZ_HIST = (size_t)M * NTAG * 4; // 2228224
  const size_t SZ_HX = 2ull * 2 * 16 * 1024 * 4;  // 262144 (double-buffered exchange)
  const size_t SZ_CNT = 32 * 16 * 4;              // 2048 (padded barrier counters)
  float* xp = (float*)(ws);
  float* h0 = (float*)(ws + SZ_XP);
  float* h1 = (float*)(ws + SZ_XP + SZ_H);
  float* em = (float*)(ws + SZ_XP + 2 * SZ_H);
  int* hist = (int*)(ws + SZ_XP + 2 * SZ_H + SZ_EM);
  char* sync0 = ws + SZ_XP + 2 * SZ_H + SZ_EM + SZ_HIST;
  float* hx0 = (float*)(sync0);
  int* cnt0 = (int*)(sync0 + SZ_HX);
  float* hx1 = (float*)(sync0 + SZ_HX + SZ_CNT);
  int* cnt1 = (int*)(sync0 + 2 * SZ_HX + SZ_CNT);

  // Zero both layers' exchange buffers + barrier counters (ws is 0xAA-poisoned)
  hipMemsetAsync(sync0, 0, 2 * (SZ_HX + SZ_CNT), stream);

  // 1. Layer-0 input projection (fused embedding gather): xp[dir][m][1024]
  gemm_k<<<dim3(M / 64, 32), 256, 0, stream>>>(embed, x, w_ih0, b_ih0, b_hh0,
                                               xp, M, 256, 2048, 1);
  // 2. Layer-0 recurrence -> h0[m][512]
  lstm_fused<<<256, 256, 0, stream>>>(xp, w_hh0, lens, h0, hx0, cnt0, T, B);

  // 3. Layer-1 input projection
  gemm_k<<<dim3(M / 64, 32), 256, 0, stream>>>(h0, nullptr, w_ih1, b_ih1, b_hh1,
                                               xp, M, 512, 2048, 1);
  // 4. Layer-1 recurrence -> h1[m][512]
  lstm_fused<<<256, 256, 0, stream>>>(xp, w_hh1, lens, h1, hx1, cnt1, T, B);

  // 5. Emissions: em[m][34]
  gemm_k<<<dim3(M / 64, 1), 256, 0, stream>>>(h1, nullptr, w_lin, b_lin, nullptr,
                                              em, M, 512, 34, 0);
  // 6. Viterbi decode -> outTags
  viterbi_k<<<64, 64, 0, stream>>>(em, lens, startT, endT, trans, hist, outTags,
                                   T, B);
  (void)in_sizes; (void)n_in; (void)out_size; (void)ws_size;
}

// Round 3
// 3036.127 us; speedup vs baseline: 2.7185x; 2.7185x over previous
//
#include <hip/hip_runtime.h>
#include <cstddef>
#include <cstdint>

// Problem constants
#define TT 256
#define BB 64
#define NTAG 34
// M = TT*BB = 16384

__device__ __forceinline__ float sigf(float x) { return 1.0f / (1.0f + expf(-x)); }

// ---------------------------------------------------------------------------
// fp32 tiled GEMM: out[m][n] = sum_k A[m][k] * W[n][k] + biasA[n] (+ biasB[n])
// (unchanged from round 1; ~0.8 ms total across 3 calls — not the bottleneck)
// ---------------------------------------------------------------------------
__global__ __launch_bounds__(256) void gemm_k(
    const float* __restrict__ Abase, const int* __restrict__ gidx,
    const float* __restrict__ W, const float* __restrict__ biasA,
    const float* __restrict__ biasB, float* __restrict__ out,
    int M, int K, int Nvalid, int xp_mode) {
  __shared__ float As[32][68];
  __shared__ float Bs[32][68];
  int tid = threadIdx.x;
  int m0 = blockIdx.x * 64;
  int n0 = blockIdx.y * 64;
  int tx = tid & 15, ty = tid >> 4;
  int lk = (tid & 7) * 4;
  int lr = tid >> 3;

  float acc[4][4] = {};

  const float* arow0;
  const float* arow1;
  {
    int ma = m0 + lr, mb = m0 + lr + 32;
    size_t ra = gidx ? (size_t)gidx[ma] : (size_t)ma;
    size_t rb = gidx ? (size_t)gidx[mb] : (size_t)mb;
    arow0 = Abase + ra * (size_t)K;
    arow1 = Abase + rb * (size_t)K;
  }
  int nA = n0 + lr, nB = n0 + lr + 32;
  const float* wr0 = W + (size_t)nA * K;
  const float* wr1 = W + (size_t)nB * K;
  bool v0 = nA < Nvalid, v1 = nB < Nvalid;

  for (int k0 = 0; k0 < K; k0 += 32) {
    float4 a0 = *(const float4*)(arow0 + k0 + lk);
    float4 a1 = *(const float4*)(arow1 + k0 + lk);
    float4 b0 = v0 ? *(const float4*)(wr0 + k0 + lk) : make_float4(0, 0, 0, 0);
    float4 b1 = v1 ? *(const float4*)(wr1 + k0 + lk) : make_float4(0, 0, 0, 0);
    __syncthreads();
    As[lk + 0][lr] = a0.x; As[lk + 1][lr] = a0.y; As[lk + 2][lr] = a0.z; As[lk + 3][lr] = a0.w;
    As[lk + 0][lr + 32] = a1.x; As[lk + 1][lr + 32] = a1.y; As[lk + 2][lr + 32] = a1.z; As[lk + 3][lr + 32] = a1.w;
    Bs[lk + 0][lr] = b0.x; Bs[lk + 1][lr] = b0.y; Bs[lk + 2][lr] = b0.z; Bs[lk + 3][lr] = b0.w;
    Bs[lk + 0][lr + 32] = b1.x; Bs[lk + 1][lr + 32] = b1.y; Bs[lk + 2][lr + 32] = b1.z; Bs[lk + 3][lr + 32] = b1.w;
    __syncthreads();
#pragma unroll
    for (int k = 0; k < 32; ++k) {
      float4 av = *(const float4*)&As[k][ty * 4];
      float4 bv = *(const float4*)&Bs[k][tx * 4];
#pragma unroll
      for (int i = 0; i < 4; ++i) {
        float a = (&av.x)[i];
        acc[i][0] += a * bv.x;
        acc[i][1] += a * bv.y;
        acc[i][2] += a * bv.z;
        acc[i][3] += a * bv.w;
      }
    }
  }
#pragma unroll
  for (int i = 0; i < 4; ++i) {
    int m = m0 + ty * 4 + i;
#pragma unroll
    for (int j = 0; j < 4; ++j) {
      int n = n0 + tx * 4 + j;
      if (n < Nvalid) {
        float v = acc[i][j] + biasA[n] + (biasB ? biasB[n] : 0.0f);
        if (xp_mode)
          out[((size_t)(n >> 10) * M + m) * 1024 + (n & 1023)] = v;
        else
          out[(size_t)m * Nvalid + n] = v;
      }
    }
  }
}

// ---------------------------------------------------------------------------
// Register-stationary LSTM recurrence, v2 (relaxed-only exchange).
// 256 blocks x 512 threads = 2 dir x 8 unit-slices(32 units) x 16 bg(4 batch).
// blk: js = blk>>5 (slice), inner = blk&31 -> d = inner>>4, bg = inner&15.
// Exchange partners share `inner` (== mod 32 -> same XCD slot under
// round-robin dispatch; heuristic only, correctness is agent-scope).
// Thread (jl=tid>>4, kseg=tid&15) holds w[4][16] (k = kseg+16i) = 64 VGPRs.
// Per step: poll 8 per-block monotonic flags (RELAXED loads only -> plain
// read-through, NO cache invalidates: round-2's 342 MB WRITE_SIZE came from
// acquire/release L2 writeback-invalidate storms) -> load 1 KB h -> 256 FMA
// -> 16-lane butterfly -> gates -> stage h slice in LDS -> 128 consecutive
// relaxed stores -> __syncthreads (drains vmcnt) -> 1 relaxed flag store.
// Double-buffered hx slots; 2-deep pipeline makes overwrite-before-read
// impossible. No counter RMW anywhere.
// ---------------------------------------------------------------------------
__global__ __launch_bounds__(512) void lstm_fused2(
    const float* __restrict__ xp,    // [2][M][1024]
    const float* __restrict__ whh,   // [2][1024][256]
    const int* __restrict__ lengths,
    float* __restrict__ out,         // [M][512]
    float* hx,                       // [2 slot][2 d][16 bg][1024] (k*4+b)
    int* flags,                      // [2 d][16 bg][8 js][32 pad]
    int T, int B) {
  __shared__ float4 hS[256];   // h[k] for 4 batches
  __shared__ float xgS[512];   // [b][g][jl]
  __shared__ float stage[128]; // [jl][b]
  int blk = blockIdx.x;
  int js = blk >> 5;
  int inner = blk & 31;
  int d = inner >> 4;
  int bg = inner & 15;
  int tid = threadIdx.x;
  int jl = tid >> 4, kseg = tid & 15;
  int j = js * 32 + jl;
  size_t M = (size_t)T * B;
  int b0 = bg * 4;

  // Stationary weights: w[g][i] = whh[d][g*256+j][kseg+16i]
  float w[4][16];
#pragma unroll
  for (int g = 0; g < 4; ++g) {
    const float* wr = whh + ((size_t)d * 1024 + g * 256 + j) * 256 + kseg;
#pragma unroll
    for (int i = 0; i < 16; ++i) w[g][i] = wr[16 * i];
  }

  int batch = b0 + (kseg & 3);
  int len = lengths[batch];
  float cst = 0.0f, hst = 0.0f;

  float* hx_grp = hx + ((size_t)d * 16 + bg) * 1024;
  const size_t slotStride = (size_t)2 * 16 * 1024;  // floats per slot
  int* flg = flags + ((d * 16 + bg) * 8) * 32;      // flag[js] at +js*32

  // xg loader mapping: tid -> (lb, lg, lj)
  int lb = tid >> 7, lg = (tid >> 5) & 3, lj = tid & 31;
  const float* xg_base = xp + (size_t)d * M * 1024 + (size_t)lg * 256 + js * 32 + lj;

  for (int s = 0; s < T; ++s) {
    int t = d ? (T - 1 - s) : s;
    // xp gate bias for this step (h-independent; overlaps poll latency)
    float xv = xg_base[((size_t)t * B + b0 + lb) * 1024];
    if (s == 0) {
      if (tid < 256) hS[tid] = make_float4(0.f, 0.f, 0.f, 0.f);
    } else {
      if (tid < 8) {
        const int* fp = flg + tid * 32;
        int guard = 0;
        while (__hip_atomic_load(fp, __ATOMIC_RELAXED, __HIP_MEMORY_SCOPE_AGENT) < s) {
          if (++guard > (1 << 24)) break;  // hang-preventer
        }
      }
    }
    xgS[tid] = xv;
    __syncthreads();
    if (s > 0) {
      const float* src = hx_grp + (size_t)(s & 1) * slotStride;
      float v0 = __hip_atomic_load(src + tid, __ATOMIC_RELAXED, __HIP_MEMORY_SCOPE_AGENT);
      float v1 = __hip_atomic_load(src + 512 + tid, __ATOMIC_RELAXED, __HIP_MEMORY_SCOPE_AGENT);
      ((float*)hS)[tid] = v0;
      ((float*)hS)[512 + tid] = v1;
      __syncthreads();
    }

    // GEMV over my 16 k values for 4 gates x 4 batches
    float acc[4][4];
#pragma unroll
    for (int g = 0; g < 4; ++g)
#pragma unroll
      for (int b = 0; b < 4; ++b) acc[g][b] = 0.0f;
#pragma unroll
    for (int i = 0; i < 16; ++i) {
      float4 hv = hS[kseg + 16 * i];  // 16 addrs x 4-lane broadcast: 2-way/bank = free
#pragma unroll
      for (int g = 0; g < 4; ++g) {
        acc[g][0] += w[g][i] * hv.x;
        acc[g][1] += w[g][i] * hv.y;
        acc[g][2] += w[g][i] * hv.z;
        acc[g][3] += w[g][i] * hv.w;
      }
    }
    // Butterfly over the 16 kseg lanes -> every lane holds full sums
#pragma unroll
    for (int g = 0; g < 4; ++g)
#pragma unroll
      for (int b = 0; b < 4; ++b) {
        float v = acc[g][b];
        v += __shfl_xor(v, 1);
        v += __shfl_xor(v, 2);
        v += __shfl_xor(v, 4);
        v += __shfl_xor(v, 8);
        acc[g][b] = v;
      }

    if (kseg < 4) {
      int b = kseg;
      float ig = sigf(acc[0][b] + xgS[b * 128 + 0 * 32 + jl]);
      float fg = sigf(acc[1][b] + xgS[b * 128 + 1 * 32 + jl]);
      float gg = tanhf(acc[2][b] + xgS[b * 128 + 2 * 32 + jl]);
      float og = sigf(acc[3][b] + xgS[b * 128 + 3 * 32 + jl]);
      bool m = t < len;
      float cn = fg * cst + ig * gg;
      float hn = og * tanhf(cn);
      if (m) { cst = cn; hst = hn; }
      out[((size_t)t * B + batch) * 512 + d * 256 + j] = m ? hst : 0.0f;
      stage[jl * 4 + b] = hst;
    }
    __syncthreads();  // stage ready; also protects xgS/hS overwrite next iter
    if (s + 1 < T) {
      if (tid < 128) {
        float hv = stage[tid];
        float* dst = hx_grp + (size_t)((s + 1) & 1) * slotStride + js * 128 + tid;
        __hip_atomic_store(dst, hv, __ATOMIC_RELAXED, __HIP_MEMORY_SCOPE_AGENT);
      }
      __syncthreads();  // per-wave s_waitcnt vmcnt(0) before s_barrier -> stores drained
      if (tid == 0)
        __hip_atomic_store(flg + js * 32, s + 1, __ATOMIC_RELAXED, __HIP_MEMORY_SCOPE_AGENT);
    }
  }
}

// ---------------------------------------------------------------------------
// Viterbi: one block (one wave) per batch element. (unchanged)
// ---------------------------------------------------------------------------
__global__ __launch_bounds__(64) void viterbi_k(
    const float* __restrict__ em, const int* __restrict__ lengths,
    const float* __restrict__ startT, const float* __restrict__ endT,
    const float* __restrict__ trans, int* __restrict__ hist,
    int* __restrict__ outTags, int T, int B) {
  __shared__ float tr[NTAG * NTAG];
  __shared__ float sc[NTAG];
  __shared__ float ns[NTAG];
  int b = blockIdx.x;
  int j = threadIdx.x;
  for (int i = j; i < NTAG * NTAG; i += 64) tr[i] = trans[i];
  int len = lengths[b];
  if (j < NTAG) sc[j] = startT[j] + em[(size_t)b * NTAG + j];
  __syncthreads();
  for (int t = 1; t < T; ++t) {
    if (j < NTAG) {
      float best = -3.0e38f;
      int arg = 0;
      for (int i = 0; i < NTAG; ++i) {
        float v = sc[i] + tr[i * NTAG + j];
        if (v > best) { best = v; arg = i; }
      }
      bool m = t < len;
      float e = em[((size_t)t * B + b) * NTAG + j];
      ns[j] = m ? (best + e) : sc[j];
      hist[((size_t)(t - 1) * B + b) * NTAG + j] = m ? arg : j;
    }
    __syncthreads();
    if (j < NTAG) sc[j] = ns[j];
    __syncthreads();
  }
  if (j == 0) {
    float best = -3.0e38f;
    int arg = 0;
    for (int i = 0; i < NTAG; ++i) {
      float v = sc[i] + endT[i];
      if (v > best) { best = v; arg = i; }
    }
    int tag = arg;
    outTags[(size_t)(T - 1) * B + b] = (T - 1 < len) ? tag : 0;
    for (int t = T - 2; t >= 0; --t) {
      tag = hist[((size_t)t * B + b) * NTAG + tag];
      outTags[(size_t)t * B + b] = (t < len) ? tag : 0;
    }
  }
}

extern "C" void kernel_launch(void* const* d_in, const int* in_sizes, int n_in,
                              void* d_out, int out_size, void* d_ws, size_t ws_size,
                              hipStream_t stream) {
  const int* x = (const int*)d_in[0];
  const int* lens = (const int*)d_in[1];
  const float* embed = (const float*)d_in[2];
  const float* w_ih0 = (const float*)d_in[3];
  const float* w_hh0 = (const float*)d_in[4];
  const float* b_ih0 = (const float*)d_in[5];
  const float* b_hh0 = (const float*)d_in[6];
  const float* w_ih1 = (const float*)d_in[7];
  const float* w_hh1 = (const float*)d_in[8];
  const float* b_ih1 = (const float*)d_in[9];
  const float* b_hh1 = (const float*)d_in[10];
  const float* w_lin = (const float*)d_in[11];
  const float* b_lin = (const float*)d_in[12];
  const float* startT = (const float*)d_in[13];
  const float* endT = (const float*)d_in[14];
  const float* trans = (const float*)d_in[15];
  int* outTags = (int*)d_out;

  const int T = TT, B = BB;
  const int M = T * B;

  char* ws = (char*)d_ws;
  const size_t SZ_XP = 2ull * M * 1024 * 4;
  const size_t SZ_H = (size_t)M * 512 * 4;
  const size_t SZ_EM = (size_t)M * NTAG * 4;
  const size_t SZ_HIST = (size_t)M * NTAG * 4;
  const size_t SZ_HX = 2ull * 2 * 16 * 1024 * 4;  // 256 KB (2 slots)
  const size_t SZ_FLG = 2ull * 16 * 8 * 32 * 4;   // 32 KB (padded flags)
  float* xp = (float*)(ws);
  float* h0 = (float*)(ws + SZ_XP);
  float* h1 = (float*)(ws + SZ_XP + SZ_H);
  float* em = (float*)(ws + SZ_XP + 2 * SZ_H);
  int* hist = (int*)(ws + SZ_XP + 2 * SZ_H + SZ_EM);
  char* sync0 = ws + SZ_XP + 2 * SZ_H + SZ_EM + SZ_HIST;
  float* hx0 = (float*)(sync0);
  int* flg0 = (int*)(sync0 + SZ_HX);
  float* hx1 = (float*)(sync0 + SZ_HX + SZ_FLG);
  int* flg1 = (int*)(sync0 + 2 * SZ_HX + SZ_FLG);

  // Zero exchange buffers + flags (ws is 0xAA-poisoned each timed launch)
  hipMemsetAsync(sync0, 0, 2 * (SZ_HX + SZ_FLG), stream);

  // 1. Layer-0 input projection (fused embedding gather)
  gemm_k<<<dim3(M / 64, 32), 256, 0, stream>>>(embed, x, w_ih0, b_ih0, b_hh0,
                                               xp, M, 256, 2048, 1);
  // 2. Layer-0 recurrence
  lstm_fused2<<<256, 512, 0, stream>>>(xp, w_hh0, lens, h0, hx0, flg0, T, B);

  // 3. Layer-1 input projection
  gemm_k<<<dim3(M / 64, 32), 256, 0, stream>>>(h0, nullptr, w_ih1, b_ih1, b_hh1,
                                               xp, M, 512, 2048, 1);
  // 4. Layer-1 recurrence
  lstm_fused2<<<256, 512, 0, stream>>>(xp, w_hh1, lens, h1, hx1, flg1, T, B);

  // 5. Emissions
  gemm_k<<<dim3(M / 64, 1), 256, 0, stream>>>(h1, nullptr, w_lin, b_lin, nullptr,
                                              em, M, 512, 34, 0);
  // 6. Viterbi decode
  viterbi_k<<<64, 64, 0, stream>>>(em, lens, startT, endT, trans, hist, outTags,
                                   T, B);
  (void)in_sizes; (void)n_in; (void)out_size; (void)ws_size;
}

// Round 4
// 2841.239 us; speedup vs baseline: 2.9049x; 1.0686x over previous
//
#include <hip/hip_runtime.h>
#include <cstddef>
#include <cstdint>

// Problem constants
#define TT 256
#define BB 64
#define NTAG 34
// M = TT*BB = 16384

__device__ __forceinline__ float sigf(float x) { return 1.0f / (1.0f + expf(-x)); }

// ---------------------------------------------------------------------------
// fp32 tiled GEMM: out[m][n] = sum_k A[m][k] * W[n][k] + biasA[n] (+ biasB[n])
// (unchanged; ~750 us total across 3 calls — next round's target)
// ---------------------------------------------------------------------------
__global__ __launch_bounds__(256) void gemm_k(
    const float* __restrict__ Abase, const int* __restrict__ gidx,
    const float* __restrict__ W, const float* __restrict__ biasA,
    const float* __restrict__ biasB, float* __restrict__ out,
    int M, int K, int Nvalid, int xp_mode) {
  __shared__ float As[32][68];
  __shared__ float Bs[32][68];
  int tid = threadIdx.x;
  int m0 = blockIdx.x * 64;
  int n0 = blockIdx.y * 64;
  int tx = tid & 15, ty = tid >> 4;
  int lk = (tid & 7) * 4;
  int lr = tid >> 3;

  float acc[4][4] = {};

  const float* arow0;
  const float* arow1;
  {
    int ma = m0 + lr, mb = m0 + lr + 32;
    size_t ra = gidx ? (size_t)gidx[ma] : (size_t)ma;
    size_t rb = gidx ? (size_t)gidx[mb] : (size_t)mb;
    arow0 = Abase + ra * (size_t)K;
    arow1 = Abase + rb * (size_t)K;
  }
  int nA = n0 + lr, nB = n0 + lr + 32;
  const float* wr0 = W + (size_t)nA * K;
  const float* wr1 = W + (size_t)nB * K;
  bool v0 = nA < Nvalid, v1 = nB < Nvalid;

  for (int k0 = 0; k0 < K; k0 += 32) {
    float4 a0 = *(const float4*)(arow0 + k0 + lk);
    float4 a1 = *(const float4*)(arow1 + k0 + lk);
    float4 b0 = v0 ? *(const float4*)(wr0 + k0 + lk) : make_float4(0, 0, 0, 0);
    float4 b1 = v1 ? *(const float4*)(wr1 + k0 + lk) : make_float4(0, 0, 0, 0);
    __syncthreads();
    As[lk + 0][lr] = a0.x; As[lk + 1][lr] = a0.y; As[lk + 2][lr] = a0.z; As[lk + 3][lr] = a0.w;
    As[lk + 0][lr + 32] = a1.x; As[lk + 1][lr + 32] = a1.y; As[lk + 2][lr + 32] = a1.z; As[lk + 3][lr + 32] = a1.w;
    Bs[lk + 0][lr] = b0.x; Bs[lk + 1][lr] = b0.y; Bs[lk + 2][lr] = b0.z; Bs[lk + 3][lr] = b0.w;
    Bs[lk + 0][lr + 32] = b1.x; Bs[lk + 1][lr + 32] = b1.y; Bs[lk + 2][lr + 32] = b1.z; Bs[lk + 3][lr + 32] = b1.w;
    __syncthreads();
#pragma unroll
    for (int k = 0; k < 32; ++k) {
      float4 av = *(const float4*)&As[k][ty * 4];
      float4 bv = *(const float4*)&Bs[k][tx * 4];
#pragma unroll
      for (int i = 0; i < 4; ++i) {
        float a = (&av.x)[i];
        acc[i][0] += a * bv.x;
        acc[i][1] += a * bv.y;
        acc[i][2] += a * bv.z;
        acc[i][3] += a * bv.w;
      }
    }
  }
#pragma unroll
  for (int i = 0; i < 4; ++i) {
    int m = m0 + ty * 4 + i;
#pragma unroll
    for (int j = 0; j < 4; ++j) {
      int n = n0 + tx * 4 + j;
      if (n < Nvalid) {
        float v = acc[i][j] + biasA[n] + (biasB ? biasB[n] : 0.0f);
        if (xp_mode)
          out[((size_t)(n >> 10) * M + m) * 1024 + (n & 1023)] = v;
        else
          out[(size_t)m * Nvalid + n] = v;
      }
    }
  }
}

// ---------------------------------------------------------------------------
// Register-stationary LSTM recurrence, v3 (stamp-embedded packet exchange).
// 256 blocks x 512 threads = 2 dir x 8 unit-slices(32 units) x 16 bg(4 batch).
// Each h value is exchanged as an 8-byte packet (stamp:u32 << 32 | h-bits):
// the computing lane stores it with ONE 8-byte agent-scope relaxed atomic
// store (single-copy atomic), and consumers poll the packet itself until
// stamp == s. This removes round-3's serial chain (LDS stage -> barrier ->
// store -> vmcnt drain -> flag store -> flag poll -> h load = ~4 L3 round
// trips/step) leaving ~1 round trip: compute -> store -> poll-detect.
// Double-buffered by step parity; safe because a producer reaches step s+2
// only after observing all step-(s+1) stamps, which were written after those
// producers' step-s reads completed. 0xAA ws poison never matches a stamp,
// so no memset is needed.
// ---------------------------------------------------------------------------
__global__ __launch_bounds__(512) void lstm_fused3(
    const float* __restrict__ xp,    // [2][M][1024]
    const float* __restrict__ whh,   // [2][1024][256]
    const int* __restrict__ lengths,
    float* __restrict__ out,         // [M][512]
    unsigned long long* hx,          // [2 slot][2 d][16 bg][1024 packets]
    int T, int B) {
  __shared__ float4 hS[256];   // h[k] for 4 batches
  __shared__ float xgS[512];   // [b][g][jl]
  int blk = blockIdx.x;
  int js = blk >> 5;
  int inner = blk & 31;
  int d = inner >> 4;
  int bg = inner & 15;
  int tid = threadIdx.x;
  int jl = tid >> 4, kseg = tid & 15;
  int j = js * 32 + jl;
  size_t M = (size_t)T * B;
  int b0 = bg * 4;

  // Stationary weights: w[g][i] = whh[d][g*256+j][kseg+16i]
  float w[4][16];
#pragma unroll
  for (int g = 0; g < 4; ++g) {
    const float* wr = whh + ((size_t)d * 1024 + g * 256 + j) * 256 + kseg;
#pragma unroll
    for (int i = 0; i < 16; ++i) w[g][i] = wr[16 * i];
  }

  int batch = b0 + (kseg & 3);
  int len = lengths[batch];
  float cst = 0.0f, hst = 0.0f;

  unsigned long long* hx_grp = hx + ((size_t)d * 16 + bg) * 1024;
  const size_t slotStride = (size_t)2 * 16 * 1024;  // packets per slot

  // xg loader mapping: tid -> (lb, lg, lj)
  int lb = tid >> 7, lg = (tid >> 5) & 3, lj = tid & 31;
  const float* xg_base = xp + (size_t)d * M * 1024 + (size_t)lg * 256 + js * 32 + lj;

  for (int s = 0; s < T; ++s) {
    int t = d ? (T - 1 - s) : s;
    // xp gate bias for this step (h-independent; overlaps poll latency)
    float xv = xg_base[((size_t)t * B + b0 + lb) * 1024];
    if (s == 0) {
      if (tid < 256) hS[tid] = make_float4(0.f, 0.f, 0.f, 0.f);
    } else {
      const unsigned long long* src = hx_grp + (size_t)(s & 1) * slotStride;
      unsigned int want = (unsigned int)s;
      unsigned long long p0, p1;
      int guard = 0;
      do {
        p0 = __hip_atomic_load(src + tid, __ATOMIC_RELAXED, __HIP_MEMORY_SCOPE_AGENT);
      } while ((unsigned int)(p0 >> 32) != want && ++guard < (1 << 22));
      guard = 0;
      do {
        p1 = __hip_atomic_load(src + 512 + tid, __ATOMIC_RELAXED, __HIP_MEMORY_SCOPE_AGENT);
      } while ((unsigned int)(p1 >> 32) != want && ++guard < (1 << 22));
      ((float*)hS)[tid] = __uint_as_float((unsigned int)p0);
      ((float*)hS)[512 + tid] = __uint_as_float((unsigned int)p1);
    }
    xgS[tid] = xv;
    __syncthreads();

    // GEMV over my 16 k values for 4 gates x 4 batches
    float acc[4][4];
#pragma unroll
    for (int g = 0; g < 4; ++g)
#pragma unroll
      for (int b = 0; b < 4; ++b) acc[g][b] = 0.0f;
#pragma unroll
    for (int i = 0; i < 16; ++i) {
      float4 hv = hS[kseg + 16 * i];  // 16 addrs x 4-lane broadcast: 2-way/bank = free
#pragma unroll
      for (int g = 0; g < 4; ++g) {
        acc[g][0] += w[g][i] * hv.x;
        acc[g][1] += w[g][i] * hv.y;
        acc[g][2] += w[g][i] * hv.z;
        acc[g][3] += w[g][i] * hv.w;
      }
    }
    // Butterfly over the 16 kseg lanes -> every lane holds full sums
#pragma unroll
    for (int g = 0; g < 4; ++g)
#pragma unroll
      for (int b = 0; b < 4; ++b) {
        float v = acc[g][b];
        v += __shfl_xor(v, 1);
        v += __shfl_xor(v, 2);
        v += __shfl_xor(v, 4);
        v += __shfl_xor(v, 8);
        acc[g][b] = v;
      }

    if (kseg < 4) {
      int b = kseg;
      float ig = sigf(acc[0][b] + xgS[b * 128 + 0 * 32 + jl]);
      float fg = sigf(acc[1][b] + xgS[b * 128 + 1 * 32 + jl]);
      float gg = tanhf(acc[2][b] + xgS[b * 128 + 2 * 32 + jl]);
      float og = sigf(acc[3][b] + xgS[b * 128 + 3 * 32 + jl]);
      bool m = t < len;
      float cn = fg * cst + ig * gg;
      float hn = og * tanhf(cn);
      if (m) { cst = cn; hst = hn; }
      out[((size_t)t * B + batch) * 512 + d * 256 + j] = m ? hst : 0.0f;
      if (s + 1 < T) {
        // stamp-embedded packet: single 8B atomic store, no drain/flag needed
        unsigned long long pkt =
            ((unsigned long long)(unsigned int)(s + 1) << 32) | __float_as_uint(hst);
        unsigned long long* dst = hx_grp + (size_t)((s + 1) & 1) * slotStride +
                                  (size_t)js * 128 + jl * 4 + b;
        __hip_atomic_store(dst, pkt, __ATOMIC_RELAXED, __HIP_MEMORY_SCOPE_AGENT);
      }
    }
    __syncthreads();  // all reads of hS/xgS done before next-iter overwrite
  }
}

// ---------------------------------------------------------------------------
// Viterbi: one block (one wave) per batch element. (unchanged)
// ---------------------------------------------------------------------------
__global__ __launch_bounds__(64) void viterbi_k(
    const float* __restrict__ em, const int* __restrict__ lengths,
    const float* __restrict__ startT, const float* __restrict__ endT,
    const float* __restrict__ trans, int* __restrict__ hist,
    int* __restrict__ outTags, int T, int B) {
  __shared__ float tr[NTAG * NTAG];
  __shared__ float sc[NTAG];
  __shared__ float ns[NTAG];
  int b = blockIdx.x;
  int j = threadIdx.x;
  for (int i = j; i < NTAG * NTAG; i += 64) tr[i] = trans[i];
  int len = lengths[b];
  if (j < NTAG) sc[j] = startT[j] + em[(size_t)b * NTAG + j];
  __syncthreads();
  for (int t = 1; t < T; ++t) {
    if (j < NTAG) {
      float best = -3.0e38f;
      int arg = 0;
      for (int i = 0; i < NTAG; ++i) {
        float v = sc[i] + tr[i * NTAG + j];
        if (v > best) { best = v; arg = i; }
      }
      bool m = t < len;
      float e = em[((size_t)t * B + b) * NTAG + j];
      ns[j] = m ? (best + e) : sc[j];
      hist[((size_t)(t - 1) * B + b) * NTAG + j] = m ? arg : j;
    }
    __syncthreads();
    if (j < NTAG) sc[j] = ns[j];
    __syncthreads();
  }
  if (j == 0) {
    float best = -3.0e38f;
    int arg = 0;
    for (int i = 0; i < NTAG; ++i) {
      float v = sc[i] + endT[i];
      if (v > best) { best = v; arg = i; }
    }
    int tag = arg;
    outTags[(size_t)(T - 1) * B + b] = (T - 1 < len) ? tag : 0;
    for (int t = T - 2; t >= 0; --t) {
      tag = hist[((size_t)t * B + b) * NTAG + tag];
      outTags[(size_t)t * B + b] = (t < len) ? tag : 0;
    }
  }
}

extern "C" void kernel_launch(void* const* d_in, const int* in_sizes, int n_in,
                              void* d_out, int out_size, void* d_ws, size_t ws_size,
                              hipStream_t stream) {
  const int* x = (const int*)d_in[0];
  const int* lens = (const int*)d_in[1];
  const float* embed = (const float*)d_in[2];
  const float* w_ih0 = (const float*)d_in[3];
  const float* w_hh0 = (const float*)d_in[4];
  const float* b_ih0 = (const float*)d_in[5];
  const float* b_hh0 = (const float*)d_in[6];
  const float* w_ih1 = (const float*)d_in[7];
  const float* w_hh1 = (const float*)d_in[8];
  const float* b_ih1 = (const float*)d_in[9];
  const float* b_hh1 = (const float*)d_in[10];
  const float* w_lin = (const float*)d_in[11];
  const float* b_lin = (const float*)d_in[12];
  const float* startT = (const float*)d_in[13];
  const float* endT = (const float*)d_in[14];
  const float* trans = (const float*)d_in[15];
  int* outTags = (int*)d_out;

  const int T = TT, B = BB;
  const int M = T * B;

  char* ws = (char*)d_ws;
  const size_t SZ_XP = 2ull * M * 1024 * 4;
  const size_t SZ_H = (size_t)M * 512 * 4;
  const size_t SZ_EM = (size_t)M * NTAG * 4;
  const size_t SZ_HIST = (size_t)M * NTAG * 4;
  const size_t SZ_HX = 2ull * 2 * 16 * 1024 * 8;  // 512 KB (2 slots, 8B packets)
  float* xp = (float*)(ws);
  float* h0 = (float*)(ws + SZ_XP);
  float* h1 = (float*)(ws + SZ_XP + SZ_H);
  float* em = (float*)(ws + SZ_XP + 2 * SZ_H);
  int* hist = (int*)(ws + SZ_XP + 2 * SZ_H + SZ_EM);
  unsigned long long* hx0 = (unsigned long long*)(ws + SZ_XP + 2 * SZ_H + SZ_EM + SZ_HIST);
  unsigned long long* hx1 = hx0 + 2ull * 2 * 16 * 1024;
  // No memset needed: 0xAA poison never matches a stamp value 1..255.

  // 1. Layer-0 input projection (fused embedding gather)
  gemm_k<<<dim3(M / 64, 32), 256, 0, stream>>>(embed, x, w_ih0, b_ih0, b_hh0,
                                               xp, M, 256, 2048, 1);
  // 2. Layer-0 recurrence
  lstm_fused3<<<256, 512, 0, stream>>>(xp, w_hh0, lens, h0, hx0, T, B);

  // 3. Layer-1 input projection
  gemm_k<<<dim3(M / 64, 32), 256, 0, stream>>>(h0, nullptr, w_ih1, b_ih1, b_hh1,
                                               xp, M, 512, 2048, 1);
  // 4. Layer-1 recurrence
  lstm_fused3<<<256, 512, 0, stream>>>(xp, w_hh1, lens, h1, hx1, T, B);

  // 5. Emissions
  gemm_k<<<dim3(M / 64, 1), 256, 0, stream>>>(h1, nullptr, w_lin, b_lin, nullptr,
                                              em, M, 512, 34, 0);
  // 6. Viterbi decode
  viterbi_k<<<64, 64, 0, stream>>>(em, lens, startT, endT, trans, hist, outTags,
                                   T, B);
  (void)in_sizes; (void)n_in; (void)out_size; (void)ws_size;
}